// Round 1
// baseline (205.005 us; speedup 1.0000x reference)
//
#include <hip/hip_runtime.h>

#define NL 30

__global__ __launch_bounds__(256) void drn_kernel(
    const float* __restrict__ x1, const float* __restrict__ x2,
    const float* __restrict__ W1, const float* __restrict__ b1,
    const float* __restrict__ W2,
    float* __restrict__ o1, float* __restrict__ o2, int nrows)
{
    // Params staged to LDS: layer l at sp[l*12] = {w1[0..4], b, w2[0..4], pad}
    // 12 floats/layer -> 48B stride, 16B aligned -> 3x ds_read_b128 per layer,
    // uniform address across the wave (broadcast, conflict-free).
    __shared__ __align__(16) float sp[NL * 12];
    for (int i = threadIdx.x; i < NL * 12; i += blockDim.x) {
        int l = i / 12, k = i % 12;
        float v = 0.0f;
        if (k < 5)        v = W1[l * 5 + k];
        else if (k == 5)  v = b1[l];
        else if (k < 11)  v = W2[l * 5 + (k - 6)];
        sp[i] = v;
    }
    __syncthreads();

    long t = (long)blockIdx.x * blockDim.x + threadIdx.x;
    long row0 = t * 4;
    if (row0 >= nrows) return;

    // Load 4 rows: x1 -> one float4, x2 -> 20 floats = 5 float4 (80B aligned).
    float h1[4];
    float h2[20];
    *(float4*)&h1[0] = *(const float4*)(x1 + row0);
    const float4* px2 = (const float4*)(x2 + row0 * 5);
    #pragma unroll
    for (int i = 0; i < 5; ++i) ((float4*)h2)[i] = px2[i];

    for (int l = 0; l < NL; ++l) {
        float4 p0 = *(const float4*)&sp[l * 12];
        float4 p1 = *(const float4*)&sp[l * 12 + 4];
        float4 p2 = *(const float4*)&sp[l * 12 + 8];
        float w1r[5] = {p0.x, p0.y, p0.z, p0.w, p1.x};
        float bb     = p1.y;
        float w2r[5] = {p1.z, p1.w, p2.x, p2.y, p2.z};
        #pragma unroll
        for (int r = 0; r < 4; ++r) {
            float s = bb;
            #pragma unroll
            for (int j = 0; j < 5; ++j)
                s = fmaf(fmaxf(h2[r * 5 + j], 0.0f), w1r[j], s);
            h1[r] += s;
            float rh = fmaxf(h1[r], 0.0f);
            #pragma unroll
            for (int j = 0; j < 5; ++j)
                h2[r * 5 + j] = fmaf(rh, w2r[j], h2[r * 5 + j]);
        }
    }

    *(float4*)(o1 + row0) = *(float4*)&h1[0];
    float4* po2 = (float4*)(o2 + row0 * 5);
    #pragma unroll
    for (int i = 0; i < 5; ++i) po2[i] = ((float4*)h2)[i];
}

extern "C" void kernel_launch(void* const* d_in, const int* in_sizes, int n_in,
                              void* d_out, int out_size, void* d_ws, size_t ws_size,
                              hipStream_t stream) {
    const float* x1 = (const float*)d_in[0];
    const float* x2 = (const float*)d_in[1];
    const float* W1 = (const float*)d_in[2];
    const float* b1 = (const float*)d_in[3];
    const float* W2 = (const float*)d_in[4];
    int nrows = in_sizes[0];            // 4,194,304
    float* o1 = (float*)d_out;          // [nrows]
    float* o2 = (float*)d_out + nrows;  // [nrows*5]

    int nthreads = nrows / 4;           // 4 rows per thread
    int block = 256;
    int grid = (nthreads + block - 1) / block;
    drn_kernel<<<grid, block, 0, stream>>>(x1, x2, W1, b1, W2, o1, o2, nrows);
}